// Round 9
// baseline (450.223 us; speedup 1.0000x reference)
//
#include <hip/hip_runtime.h>
#include <hip/hip_bf16.h>

#define D_MODEL 1024
#define N_HEAD  16
#define D_K     64
#define FFN_DIM 4096
#define B_SZ    2
#define L_SEQ   2048
#define ROWS    (B_SZ * L_SEQ)   // 4096
#define PST     68               // attention LDS row stride (shorts): 34 words == 2 mod 32

typedef float  floatx4 __attribute__((ext_vector_type(4)));
typedef short  shortx8 __attribute__((ext_vector_type(8)));

__device__ __forceinline__ unsigned short f2bf(float f) {
    unsigned int u = __float_as_uint(f);
    unsigned int rounding = 0x7fffu + ((u >> 16) & 1u);
    return (unsigned short)((u + rounding) >> 16);
}
__device__ __forceinline__ float bf2f(unsigned short u) {
    return __uint_as_float(((unsigned int)u) << 16);
}

// async global->LDS 16B copy; LDS dest must be wave-uniform base + lane*16
__device__ __forceinline__ void glds16(const unsigned short* g, unsigned short* l) {
    __builtin_amdgcn_global_load_lds(
        (const __attribute__((address_space(1))) unsigned int*)g,
        (__attribute__((address_space(3))) unsigned int*)l, 16, 0, 0);
}

// ---------- LayerNorm: one block per row of 1024, fp32 in -> bf16 out ----------
__global__ __launch_bounds__(256) void ln_kernel(const float* __restrict__ x,
                                                 const float* __restrict__ g,
                                                 const float* __restrict__ b,
                                                 unsigned short* __restrict__ out) {
    const int row = blockIdx.x;
    const int tid = threadIdx.x;
    const float* xr = x + (size_t)row * D_MODEL;
    float4 xv = *reinterpret_cast<const float4*>(&xr[tid * 4]);
    float v[4] = {xv.x, xv.y, xv.z, xv.w};
    float s = v[0] + v[1] + v[2] + v[3];
    float ss = v[0] * v[0] + v[1] * v[1] + v[2] * v[2] + v[3] * v[3];
    __shared__ float r1[256], r2[256];
    r1[tid] = s; r2[tid] = ss;
    __syncthreads();
    for (int off = 128; off > 0; off >>= 1) {
        if (tid < off) { r1[tid] += r1[tid + off]; r2[tid] += r2[tid + off]; }
        __syncthreads();
    }
    const float mean = r1[0] * (1.0f / D_MODEL);
    const float var  = r2[0] * (1.0f / D_MODEL) - mean * mean;
    const float inv  = rsqrtf(var + 1e-5f);
    unsigned short* orow = out + (size_t)row * D_MODEL;
    ushort4 o;
    o.x = f2bf((v[0] - mean) * inv * g[tid * 4 + 0] + b[tid * 4 + 0]);
    o.y = f2bf((v[1] - mean) * inv * g[tid * 4 + 1] + b[tid * 4 + 1]);
    o.z = f2bf((v[2] - mean) * inv * g[tid * 4 + 2] + b[tid * 4 + 2]);
    o.w = f2bf((v[3] - mean) * inv * g[tid * 4 + 3] + b[tid * 4 + 3]);
    *reinterpret_cast<ushort4*>(&orow[tid * 4]) = o;
}

// ---------- Transpose+cast: W fp32 [K][N] -> Wt bf16 [N][K] ----------
__global__ __launch_bounds__(256) void transpose_cast(const float* __restrict__ W,
                                                      unsigned short* __restrict__ Wt,
                                                      int K, int N) {
    __shared__ unsigned short T[32][33];
    const int t = threadIdx.x;
    const int k0 = blockIdx.y * 32, n0 = blockIdx.x * 32;
    const int kr = t >> 3, nc = (t & 7) * 4;
    float4 w = *reinterpret_cast<const float4*>(&W[(size_t)(k0 + kr) * N + n0 + nc]);
    T[kr][nc + 0] = f2bf(w.x); T[kr][nc + 1] = f2bf(w.y);
    T[kr][nc + 2] = f2bf(w.z); T[kr][nc + 3] = f2bf(w.w);
    __syncthreads();
    const int nr = t >> 3, kc = (t & 7) * 4;
    ushort4 o;
    o.x = T[kc + 0][nr]; o.y = T[kc + 1][nr];
    o.z = T[kc + 2][nr]; o.w = T[kc + 3][nr];
    *reinterpret_cast<ushort4*>(&Wt[(size_t)(n0 + nr) * K + k0 + kc]) = o;
}

// ---------- 4x square (1024x1024) transpose in one dispatch, z selects matrix ----------
__global__ __launch_bounds__(256) void transpose_cast4(const float* s0, const float* s1,
                                                       const float* s2, const float* s3,
                                                       unsigned short* d0, unsigned short* d1,
                                                       unsigned short* d2, unsigned short* d3) {
    const int z = blockIdx.z;
    const float* W = (z == 0) ? s0 : (z == 1) ? s1 : (z == 2) ? s2 : s3;
    unsigned short* Wt = (z == 0) ? d0 : (z == 1) ? d1 : (z == 2) ? d2 : d3;
    __shared__ unsigned short T[32][33];
    const int t = threadIdx.x;
    const int k0 = blockIdx.y * 32, n0 = blockIdx.x * 32;
    const int kr = t >> 3, nc = (t & 7) * 4;
    float4 w = *reinterpret_cast<const float4*>(&W[(size_t)(k0 + kr) * D_MODEL + n0 + nc]);
    T[kr][nc + 0] = f2bf(w.x); T[kr][nc + 1] = f2bf(w.y);
    T[kr][nc + 2] = f2bf(w.z); T[kr][nc + 3] = f2bf(w.w);
    __syncthreads();
    const int nr = t >> 3, kc = (t & 7) * 4;
    ushort4 o;
    o.x = T[kc + 0][nr]; o.y = T[kc + 1][nr];
    o.z = T[kc + 2][nr]; o.w = T[kc + 3][nr];
    *reinterpret_cast<ushort4*>(&Wt[(size_t)(n0 + nr) * D_MODEL + k0 + kc]) = o;
}

// ---------- MFMA bf16 GEMM (async staging). A [M][K]; Wt [N][K]. 128x128, BK=32. ----------
template <int SILU, int HAS_RES, int OUT_BF16>
__global__ __launch_bounds__(256) void mfma_gemm(const unsigned short* __restrict__ A,
                                                 const unsigned short* __restrict__ Wt,
                                                 const float* __restrict__ bias,
                                                 const float* __restrict__ res,
                                                 void* __restrict__ outP,
                                                 int M, int N, int K) {
    __shared__ unsigned short As[128 * 32];
    __shared__ unsigned short Bs[128 * 32];
    const int tid  = threadIdx.x;
    const int lane = tid & 63;
    const int wave = tid >> 6;
    const int row0 = blockIdx.y * 128, col0 = blockIdx.x * 128;
    const int wr = (wave >> 1) * 64, wc = (wave & 1) * 64;

    floatx4 acc[4][4] = {};
    const int c0 = tid,       r0s = c0 >> 2, k0s = (c0 & 3) * 8;
    const int c1 = tid + 256, r1s = c1 >> 2, k1s = (c1 & 3) * 8;
    const int am = (lane & 15), aq = (lane >> 4) * 8;

    for (int kt = 0; kt < K; kt += 32) {
        glds16(A  + (size_t)(row0 + r0s) * K + kt + k0s, &As[c0 * 8]);
        glds16(A  + (size_t)(row0 + r1s) * K + kt + k1s, &As[c1 * 8]);
        glds16(Wt + (size_t)(col0 + r0s) * K + kt + k0s, &Bs[c0 * 8]);
        glds16(Wt + (size_t)(col0 + r1s) * K + kt + k1s, &Bs[c1 * 8]);
        __syncthreads();
        shortx8 af[4], bf[4];
#pragma unroll
        for (int i = 0; i < 4; ++i)
            af[i] = *reinterpret_cast<const shortx8*>(&As[(wr + i * 16 + am) * 32 + aq]);
#pragma unroll
        for (int j = 0; j < 4; ++j)
            bf[j] = *reinterpret_cast<const shortx8*>(&Bs[(wc + j * 16 + am) * 32 + aq]);
#pragma unroll
        for (int i = 0; i < 4; ++i)
#pragma unroll
            for (int j = 0; j < 4; ++j)
                acc[i][j] = __builtin_amdgcn_mfma_f32_16x16x32_bf16(af[i], bf[j], acc[i][j], 0, 0, 0);
        __syncthreads();
    }

    const int cq = (lane >> 4) * 4;
    const int cn = lane & 15;
#pragma unroll
    for (int i = 0; i < 4; ++i) {
#pragma unroll
        for (int j = 0; j < 4; ++j) {
            const int n = col0 + wc + j * 16 + cn;
            const float bb = bias[n];
#pragma unroll
            for (int r = 0; r < 4; ++r) {
                const int m = row0 + wr + i * 16 + cq + r;
                float v = acc[i][j][r] + bb;
                if (SILU) v = v / (1.0f + __expf(-v));
                if (HAS_RES) v += res[(size_t)m * N + n];
                if (OUT_BF16) ((unsigned short*)outP)[(size_t)m * N + n] = f2bf(v);
                else          ((float*)outP)[(size_t)m * N + n] = v;
            }
        }
    }
}

// ---------- Fused QKV GEMM: N=3072 over concatenated [3072][1024] weights ----------
// col block 0..7 -> Q (pre-scaled by 1/8), 8..15 -> K, 16..23 -> V (transposed [1024][ROWS])
__global__ __launch_bounds__(256) void mfma_gemm_qkv(const unsigned short* __restrict__ A,
                                                     const unsigned short* __restrict__ Wt,
                                                     const float* __restrict__ bq,
                                                     const float* __restrict__ bk,
                                                     const float* __restrict__ bv,
                                                     unsigned short* __restrict__ qb,
                                                     unsigned short* __restrict__ kb,
                                                     unsigned short* __restrict__ vtb) {
    const int K = D_MODEL, M = ROWS;
    __shared__ unsigned short As[128 * 32];
    __shared__ unsigned short Bs[128 * 32];
    const int tid  = threadIdx.x;
    const int lane = tid & 63;
    const int wave = tid >> 6;
    const int row0 = blockIdx.y * 128, col0 = blockIdx.x * 128;
    const int wr = (wave >> 1) * 64, wc = (wave & 1) * 64;

    floatx4 acc[4][4] = {};
    const int c0 = tid,       r0s = c0 >> 2, k0s = (c0 & 3) * 8;
    const int c1 = tid + 256, r1s = c1 >> 2, k1s = (c1 & 3) * 8;
    const int am = (lane & 15), aq = (lane >> 4) * 8;

    for (int kt = 0; kt < K; kt += 32) {
        glds16(A  + (size_t)(row0 + r0s) * K + kt + k0s, &As[c0 * 8]);
        glds16(A  + (size_t)(row0 + r1s) * K + kt + k1s, &As[c1 * 8]);
        glds16(Wt + (size_t)(col0 + r0s) * K + kt + k0s, &Bs[c0 * 8]);
        glds16(Wt + (size_t)(col0 + r1s) * K + kt + k1s, &Bs[c1 * 8]);
        __syncthreads();
        shortx8 af[4], bf[4];
#pragma unroll
        for (int i = 0; i < 4; ++i)
            af[i] = *reinterpret_cast<const shortx8*>(&As[(wr + i * 16 + am) * 32 + aq]);
#pragma unroll
        for (int j = 0; j < 4; ++j)
            bf[j] = *reinterpret_cast<const shortx8*>(&Bs[(wc + j * 16 + am) * 32 + aq]);
#pragma unroll
        for (int i = 0; i < 4; ++i)
#pragma unroll
            for (int j = 0; j < 4; ++j)
                acc[i][j] = __builtin_amdgcn_mfma_f32_16x16x32_bf16(af[i], bf[j], acc[i][j], 0, 0, 0);
        __syncthreads();
    }

    const int cq = (lane >> 4) * 4;
    const int cn = lane & 15;
    const int sel = col0 >> 10;                 // 0=Q 1=K 2=V (block-uniform)
    const int nbase = col0 & 1023;
    const float* bias = (sel == 0) ? bq : (sel == 1) ? bk : bv;
    const float scl = (sel == 0) ? 0.125f : 1.0f;   // fold 1/sqrt(Dk) into Q (exact)
#pragma unroll
    for (int i = 0; i < 4; ++i) {
#pragma unroll
        for (int j = 0; j < 4; ++j) {
            const int n = nbase + wc + j * 16 + cn;
            const float bb = bias[n];
            if (sel == 2) {
                const int m0 = row0 + wr + i * 16 + cq;
                ushort4 o;
                o.x = f2bf(acc[i][j][0] + bb);
                o.y = f2bf(acc[i][j][1] + bb);
                o.z = f2bf(acc[i][j][2] + bb);
                o.w = f2bf(acc[i][j][3] + bb);
                *reinterpret_cast<ushort4*>(&vtb[(size_t)n * M + m0]) = o;
            } else {
                unsigned short* dst = (sel == 0) ? qb : kb;
#pragma unroll
                for (int r = 0; r < 4; ++r) {
                    const int m = row0 + wr + i * 16 + cq + r;
                    dst[(size_t)m * D_MODEL + n] = f2bf((acc[i][j][r] + bb) * scl);
                }
            }
        }
    }
}

// ---------- Split-K GEMM: z = K-slice; raw bf16 partials ----------
__global__ __launch_bounds__(256) void mfma_gemm_splitk(const unsigned short* __restrict__ A,
                                                        const unsigned short* __restrict__ Wt,
                                                        unsigned short* __restrict__ parts,
                                                        int M, int N, int KS) {
    __shared__ unsigned short As[128 * 32];
    __shared__ unsigned short Bs[128 * 32];
    const int tid  = threadIdx.x;
    const int lane = tid & 63;
    const int wave = tid >> 6;
    const int row0 = blockIdx.y * 128, col0 = blockIdx.x * 128;
    const int wr = (wave >> 1) * 64, wc = (wave & 1) * 64;
    const int K = KS * gridDim.z;
    const int kbeg = blockIdx.z * KS;
    unsigned short* outp = parts + (size_t)blockIdx.z * M * N;

    floatx4 acc[4][4] = {};
    const int c0 = tid,       r0s = c0 >> 2, k0s = (c0 & 3) * 8;
    const int c1 = tid + 256, r1s = c1 >> 2, k1s = (c1 & 3) * 8;
    const int am = (lane & 15), aq = (lane >> 4) * 8;

    for (int kt = kbeg; kt < kbeg + KS; kt += 32) {
        glds16(A  + (size_t)(row0 + r0s) * K + kt + k0s, &As[c0 * 8]);
        glds16(A  + (size_t)(row0 + r1s) * K + kt + k1s, &As[c1 * 8]);
        glds16(Wt + (size_t)(col0 + r0s) * K + kt + k0s, &Bs[c0 * 8]);
        glds16(Wt + (size_t)(col0 + r1s) * K + kt + k1s, &Bs[c1 * 8]);
        __syncthreads();
        shortx8 af[4], bf[4];
#pragma unroll
        for (int i = 0; i < 4; ++i)
            af[i] = *reinterpret_cast<const shortx8*>(&As[(wr + i * 16 + am) * 32 + aq]);
#pragma unroll
        for (int j = 0; j < 4; ++j)
            bf[j] = *reinterpret_cast<const shortx8*>(&Bs[(wc + j * 16 + am) * 32 + aq]);
#pragma unroll
        for (int i = 0; i < 4; ++i)
#pragma unroll
            for (int j = 0; j < 4; ++j)
                acc[i][j] = __builtin_amdgcn_mfma_f32_16x16x32_bf16(af[i], bf[j], acc[i][j], 0, 0, 0);
        __syncthreads();
    }

    const int cq = (lane >> 4) * 4;
    const int cn = lane & 15;
#pragma unroll
    for (int i = 0; i < 4; ++i)
#pragma unroll
        for (int j = 0; j < 4; ++j) {
            const int n = col0 + wc + j * 16 + cn;
#pragma unroll
            for (int r = 0; r < 4; ++r) {
                const int m = row0 + wr + i * 16 + cq + r;
                outp[(size_t)m * N + n] = f2bf(acc[i][j][r]);
            }
        }
}

// ---------- combine: out = p0 + p1 + bias + res ----------
__global__ __launch_bounds__(256) void combine_kernel(const unsigned short* __restrict__ p0,
                                                      const unsigned short* __restrict__ p1,
                                                      const float* __restrict__ bias,
                                                      const float* __restrict__ res,
                                                      float* __restrict__ out) {
    const size_t e0 = ((size_t)blockIdx.x * 256 + threadIdx.x) * 4;
    const int col = (int)(e0 & 1023);
    ushort4 a = *reinterpret_cast<const ushort4*>(&p0[e0]);
    ushort4 b = *reinterpret_cast<const ushort4*>(&p1[e0]);
    float4 r = *reinterpret_cast<const float4*>(&res[e0]);
    float4 o;
    o.x = bf2f(a.x) + bf2f(b.x) + bias[col + 0] + r.x;
    o.y = bf2f(a.y) + bf2f(b.y) + bias[col + 1] + r.y;
    o.z = bf2f(a.z) + bf2f(b.z) + bias[col + 2] + r.z;
    o.w = bf2f(a.w) + bf2f(b.w) + bias[col + 3] + r.w;
    *reinterpret_cast<float4*>(&out[e0]) = o;
}

// ---------- MFMA attention: one block per (b, h, 128-q-tile); 4 waves; 2 strips/wave
// Q (pre-scaled 1/8), K bf16 [B*L][H*Dk]; Vt bf16 [H*Dk][B*L]; att bf16 [B*L][H*Dk].
__global__ __launch_bounds__(256) void attn_mfma(const unsigned short* __restrict__ Q,
                                                 const unsigned short* __restrict__ K,
                                                 const unsigned short* __restrict__ Vt,
                                                 const int* __restrict__ mask,
                                                 unsigned short* __restrict__ att) {
    const int tid  = threadIdx.x;
    const int lane = tid & 63;
    const int wave = tid >> 6;
    const int q0 = blockIdx.x * 128;
    const int h  = blockIdx.y;
    const int b  = blockIdx.z;

    __shared__ unsigned short Qs[128 * PST];   // [m][k]
    __shared__ unsigned short Ks[64 * PST];    // [j][k]
    __shared__ unsigned short Vs[64 * PST];    // [d][j]
    __shared__ unsigned short Ps[128 * PST];   // [m][j]
    __shared__ int mk[64];

    const int am = lane & 15;
    const int aq = (lane >> 4) * 8;
    const int cq = (lane >> 4) * 4;
    const int cn = lane & 15;

    // stage Q tile: 128 rows x 64 shorts = 1024 chunks of 8 shorts
    for (int c = tid; c < 1024; c += 256) {
        const int r = c >> 3, off = (c & 7) * 8;
        *reinterpret_cast<uint4*>(&Qs[r * PST + off]) =
            *reinterpret_cast<const uint4*>(&Q[(size_t)(b * L_SEQ + q0 + r) * D_MODEL + h * D_K + off]);
    }
    __syncthreads();

    shortx8 aQ[2][2];
#pragma unroll
    for (int s = 0; s < 2; ++s) {
        aQ[s][0] = *reinterpret_cast<const shortx8*>(&Qs[(s * 64 + wave * 16 + am) * PST + aq]);
        aQ[s][1] = *reinterpret_cast<const shortx8*>(&Qs[(s * 64 + wave * 16 + am) * PST + 32 + aq]);
    }

    floatx4 oacc[2][4] = {};
    float lsum[2][4] = {};

    for (int j0 = 0; j0 < L_SEQ; j0 += 64) {
        __syncthreads();
        for (int c = tid; c < 512; c += 256) {
            const int r = c >> 3, off = (c & 7) * 8;
            *reinterpret_cast<uint4*>(&Ks[r * PST + off]) =
                *reinterpret_cast<const uint4*>(&K[(size_t)(b * L_SEQ + j0 + r) * D_MODEL + h * D_K + off]);
            *reinterpret_cast<uint4*>(&Vs[r * PST + off]) =
                *reinterpret_cast<const uint4*>(&Vt[(size_t)(h * D_K + r) * ROWS + b * L_SEQ + j0 + off]);
        }
        if (tid < 64) mk[tid] = mask[b * L_SEQ + j0 + tid];
        __syncthreads();

#pragma unroll
        for (int s = 0; s < 2; ++s) {
            floatx4 sacc[4] = {};
#pragma unroll
            for (int kt = 0; kt < 2; ++kt)
#pragma unroll
                for (int jt = 0; jt < 4; ++jt) {
                    shortx8 bK = *reinterpret_cast<const shortx8*>(&Ks[(jt * 16 + am) * PST + kt * 32 + aq]);
                    sacc[jt] = __builtin_amdgcn_mfma_f32_16x16x32_bf16(aQ[s][kt], bK, sacc[jt], 0, 0, 0);
                }
            // P = exp(S) masked (Q pre-scaled); truncate-cast to bf16 (no RNE)
#pragma unroll
            for (int jt = 0; jt < 4; ++jt) {
                const int mv = mk[jt * 16 + cn];
#pragma unroll
                for (int r = 0; r < 4; ++r) {
                    float p = mv ? __expf(sacc[jt][r]) : 0.0f;
                    lsum[s][r] += p;
                    Ps[(s * 64 + wave * 16 + cq + r) * PST + jt * 16 + cn] =
                        (unsigned short)(__float_as_uint(p) >> 16);
                }
            }
            // O += P x V (wave-private Ps rows)
#pragma unroll
            for (int kt = 0; kt < 2; ++kt) {
                shortx8 aP = *reinterpret_cast<const shortx8*>(&Ps[(s * 64 + wave * 16 + am) * PST + kt * 32 + aq]);
#pragma unroll
                for (int dt = 0; dt < 4; ++dt) {
                    shortx8 bV = *reinterpret_cast<const shortx8*>(&Vs[(dt * 16 + am) * PST + kt * 32 + aq]);
                    oacc[s][dt] = __builtin_amdgcn_mfma_f32_16x16x32_bf16(aP, bV, oacc[s][dt], 0, 0, 0);
                }
            }
        }
    }

#pragma unroll
    for (int s = 0; s < 2; ++s) {
#pragma unroll
        for (int r = 0; r < 4; ++r) {
            float t = lsum[s][r];
            t += __shfl_xor(t, 1);
            t += __shfl_xor(t, 2);
            t += __shfl_xor(t, 4);
            t += __shfl_xor(t, 8);
            lsum[s][r] = 1.0f / t;
        }
#pragma unroll
        for (int dt = 0; dt < 4; ++dt)
#pragma unroll
            for (int r = 0; r < 4; ++r) {
                att[(size_t)(b * L_SEQ + q0 + s * 64 + wave * 16 + cq + r) * D_MODEL + h * D_K + dt * 16 + cn] =
                    f2bf(oacc[s][dt][r] * lsum[s][r]);
            }
    }
}

extern "C" void kernel_launch(void* const* d_in, const int* in_sizes, int n_in,
                              void* d_out, int out_size, void* d_ws, size_t ws_size,
                              hipStream_t stream) {
    const float* x     = (const float*)d_in[0];
    const int*   mask  = (const int*)d_in[1];
    const float* ln1_g = (const float*)d_in[2];
    const float* ln1_b = (const float*)d_in[3];
    const float* Wq    = (const float*)d_in[4];
    const float* bq    = (const float*)d_in[5];
    const float* Wk    = (const float*)d_in[6];
    const float* bk    = (const float*)d_in[7];
    const float* Wv    = (const float*)d_in[8];
    const float* bv    = (const float*)d_in[9];
    const float* Wo    = (const float*)d_in[10];
    const float* bo    = (const float*)d_in[11];
    const float* ln2_g = (const float*)d_in[12];
    const float* ln2_b = (const float*)d_in[13];
    const float* W1    = (const float*)d_in[14];
    const float* b1    = (const float*)d_in[15];
    const float* W2    = (const float*)d_in[16];
    const float* b2    = (const float*)d_in[17];
    float* out = (float*)d_out;

    float* ws = (float*)d_ws;
    const size_t SZ = (size_t)ROWS * D_MODEL;  // 4M elements; fp32 slot = 16 MB

    unsigned short* nx  = (unsigned short*)(ws + 0 * SZ);   // 0-8 MB: LN1/LN2 out bf16
    unsigned short* qb  = (unsigned short*)(ws + 1 * SZ);   // 16-24: Q bf16 (pre-scaled)
    unsigned short* kb  = qb + SZ;                          // 24-32: K bf16
    unsigned short* vtb = (unsigned short*)(ws + 2 * SZ);   // 32-40: V^T bf16
    unsigned short* attb = vtb + SZ;                        // 40-48: att bf16
    float* x1  = out;                                       // residual stream in d_out
    unsigned short* nx2 = nx;                               // slot0 reuse
    unsigned short* h = (unsigned short*)(ws + 2 * SZ);     // 32-64: FFN hidden bf16
    unsigned short* parts = (unsigned short*)(ws + 0 * SZ); // 0-16: FFN2 split-K partials

    unsigned short* WqkvT = (unsigned short*)(ws + 4 * SZ); // 64-70: concat [3072][1024]
    unsigned short* WqT = WqkvT;
    unsigned short* WkT = WqkvT + (size_t)D_MODEL * D_MODEL;
    unsigned short* WvT = WkT + (size_t)D_MODEL * D_MODEL;
    unsigned short* WoT = WvT + (size_t)D_MODEL * D_MODEL;  // 70-72
    unsigned short* W1T = (unsigned short*)(ws + 1 * SZ);   // 16-24 (qb/kb dead after attn)
    unsigned short* W2T = W1T + (size_t)D_MODEL * FFN_DIM;  // 24-32

    ln_kernel<<<ROWS, 256, 0, stream>>>(x, ln1_g, ln1_b, nx);

    transpose_cast4<<<dim3(32, 32, 4), 256, 0, stream>>>(Wq, Wk, Wv, Wo, WqT, WkT, WvT, WoT);

    mfma_gemm_qkv<<<dim3(3072 / 128, ROWS / 128), 256, 0, stream>>>(
        nx, WqkvT, bq, bk, bv, qb, kb, vtb);

    attn_mfma<<<dim3(L_SEQ / 128, N_HEAD, B_SZ), 256, 0, stream>>>(qb, kb, vtb, mask, attb);

    transpose_cast<<<dim3(FFN_DIM / 32, D_MODEL / 32), 256, 0, stream>>>(W1, W1T, D_MODEL, FFN_DIM);
    transpose_cast<<<dim3(D_MODEL / 32, FFN_DIM / 32), 256, 0, stream>>>(W2, W2T, FFN_DIM, D_MODEL);

    mfma_gemm<0, 1, 0><<<dim3(D_MODEL / 128, ROWS / 128), 256, 0, stream>>>(
        attb, WoT, bo, x, x1, ROWS, D_MODEL, D_MODEL);

    ln_kernel<<<ROWS, 256, 0, stream>>>(x1, ln2_g, ln2_b, nx2);

    mfma_gemm<1, 0, 1><<<dim3(FFN_DIM / 128, ROWS / 128), 256, 0, stream>>>(
        nx2, W1T, b1, nullptr, h, ROWS, FFN_DIM, D_MODEL);

    mfma_gemm_splitk<<<dim3(D_MODEL / 128, ROWS / 128, 2), 256, 0, stream>>>(
        h, W2T, parts, ROWS, D_MODEL, FFN_DIM / 2);
    combine_kernel<<<(ROWS * D_MODEL) / 1024, 256, 0, stream>>>(
        parts, parts + SZ, b2, x1, out);
}

// Round 10
// 435.362 us; speedup vs baseline: 1.0341x; 1.0341x over previous
//
#include <hip/hip_runtime.h>
#include <hip/hip_bf16.h>

#define D_MODEL 1024
#define N_HEAD  16
#define D_K     64
#define FFN_DIM 4096
#define B_SZ    2
#define L_SEQ   2048
#define ROWS    (B_SZ * L_SEQ)   // 4096
#define PST     68               // attention LDS row stride (shorts): 34 words == 2 mod 32

typedef float  floatx4 __attribute__((ext_vector_type(4)));
typedef short  shortx8 __attribute__((ext_vector_type(8)));

__device__ __forceinline__ unsigned short f2bf(float f) {
    unsigned int u = __float_as_uint(f);
    unsigned int rounding = 0x7fffu + ((u >> 16) & 1u);
    return (unsigned short)((u + rounding) >> 16);
}
__device__ __forceinline__ float bf2f(unsigned short u) {
    return __uint_as_float(((unsigned int)u) << 16);
}

// async global->LDS 16B copy; LDS dest must be wave-uniform base + lane*16
__device__ __forceinline__ void glds16(const unsigned short* g, unsigned short* l) {
    __builtin_amdgcn_global_load_lds(
        (const __attribute__((address_space(1))) unsigned int*)g,
        (__attribute__((address_space(3))) unsigned int*)l, 16, 0, 0);
}

// ---------- LayerNorm: one block per row of 1024, fp32 in -> bf16 out ----------
__global__ __launch_bounds__(256) void ln_kernel(const float* __restrict__ x,
                                                 const float* __restrict__ g,
                                                 const float* __restrict__ b,
                                                 unsigned short* __restrict__ out) {
    const int row = blockIdx.x;
    const int tid = threadIdx.x;
    const float* xr = x + (size_t)row * D_MODEL;
    float4 xv = *reinterpret_cast<const float4*>(&xr[tid * 4]);
    float v[4] = {xv.x, xv.y, xv.z, xv.w};
    float s = v[0] + v[1] + v[2] + v[3];
    float ss = v[0] * v[0] + v[1] * v[1] + v[2] * v[2] + v[3] * v[3];
    __shared__ float r1[256], r2[256];
    r1[tid] = s; r2[tid] = ss;
    __syncthreads();
    for (int off = 128; off > 0; off >>= 1) {
        if (tid < off) { r1[tid] += r1[tid + off]; r2[tid] += r2[tid + off]; }
        __syncthreads();
    }
    const float mean = r1[0] * (1.0f / D_MODEL);
    const float var  = r2[0] * (1.0f / D_MODEL) - mean * mean;
    const float inv  = rsqrtf(var + 1e-5f);
    unsigned short* orow = out + (size_t)row * D_MODEL;
    ushort4 o;
    o.x = f2bf((v[0] - mean) * inv * g[tid * 4 + 0] + b[tid * 4 + 0]);
    o.y = f2bf((v[1] - mean) * inv * g[tid * 4 + 1] + b[tid * 4 + 1]);
    o.z = f2bf((v[2] - mean) * inv * g[tid * 4 + 2] + b[tid * 4 + 2]);
    o.w = f2bf((v[3] - mean) * inv * g[tid * 4 + 3] + b[tid * 4 + 3]);
    *reinterpret_cast<ushort4*>(&orow[tid * 4]) = o;
}

// ---------- Transpose+cast: W fp32 [K][N] -> Wt bf16 [N][K] ----------
__global__ __launch_bounds__(256) void transpose_cast(const float* __restrict__ W,
                                                      unsigned short* __restrict__ Wt,
                                                      int K, int N) {
    __shared__ unsigned short T[32][33];
    const int t = threadIdx.x;
    const int k0 = blockIdx.y * 32, n0 = blockIdx.x * 32;
    const int kr = t >> 3, nc = (t & 7) * 4;
    float4 w = *reinterpret_cast<const float4*>(&W[(size_t)(k0 + kr) * N + n0 + nc]);
    T[kr][nc + 0] = f2bf(w.x); T[kr][nc + 1] = f2bf(w.y);
    T[kr][nc + 2] = f2bf(w.z); T[kr][nc + 3] = f2bf(w.w);
    __syncthreads();
    const int nr = t >> 3, kc = (t & 7) * 4;
    ushort4 o;
    o.x = T[kc + 0][nr]; o.y = T[kc + 1][nr];
    o.z = T[kc + 2][nr]; o.w = T[kc + 3][nr];
    *reinterpret_cast<ushort4*>(&Wt[(size_t)(n0 + nr) * K + k0 + kc]) = o;
}

// ---------- 4x square (1024x1024) transpose in one dispatch, z selects matrix ----------
__global__ __launch_bounds__(256) void transpose_cast4(const float* s0, const float* s1,
                                                       const float* s2, const float* s3,
                                                       unsigned short* d0, unsigned short* d1,
                                                       unsigned short* d2, unsigned short* d3) {
    const int z = blockIdx.z;
    const float* W = (z == 0) ? s0 : (z == 1) ? s1 : (z == 2) ? s2 : s3;
    unsigned short* Wt = (z == 0) ? d0 : (z == 1) ? d1 : (z == 2) ? d2 : d3;
    __shared__ unsigned short T[32][33];
    const int t = threadIdx.x;
    const int k0 = blockIdx.y * 32, n0 = blockIdx.x * 32;
    const int kr = t >> 3, nc = (t & 7) * 4;
    float4 w = *reinterpret_cast<const float4*>(&W[(size_t)(k0 + kr) * D_MODEL + n0 + nc]);
    T[kr][nc + 0] = f2bf(w.x); T[kr][nc + 1] = f2bf(w.y);
    T[kr][nc + 2] = f2bf(w.z); T[kr][nc + 3] = f2bf(w.w);
    __syncthreads();
    const int nr = t >> 3, kc = (t & 7) * 4;
    ushort4 o;
    o.x = T[kc + 0][nr]; o.y = T[kc + 1][nr];
    o.z = T[kc + 2][nr]; o.w = T[kc + 3][nr];
    *reinterpret_cast<ushort4*>(&Wt[(size_t)(n0 + nr) * D_MODEL + k0 + kc]) = o;
}

// ---------- MFMA bf16 GEMM (async staging). A [M][K]; Wt [N][K]. 128x128, BK=32. ----------
template <int SILU, int HAS_RES, int OUT_BF16>
__global__ __launch_bounds__(256) void mfma_gemm(const unsigned short* __restrict__ A,
                                                 const unsigned short* __restrict__ Wt,
                                                 const float* __restrict__ bias,
                                                 const float* __restrict__ res,
                                                 void* __restrict__ outP,
                                                 int M, int N, int K) {
    __shared__ unsigned short As[128 * 32];
    __shared__ unsigned short Bs[128 * 32];
    const int tid  = threadIdx.x;
    const int lane = tid & 63;
    const int wave = tid >> 6;
    const int row0 = blockIdx.y * 128, col0 = blockIdx.x * 128;
    const int wr = (wave >> 1) * 64, wc = (wave & 1) * 64;

    floatx4 acc[4][4] = {};
    const int c0 = tid,       r0s = c0 >> 2, k0s = (c0 & 3) * 8;
    const int c1 = tid + 256, r1s = c1 >> 2, k1s = (c1 & 3) * 8;
    const int am = (lane & 15), aq = (lane >> 4) * 8;

    for (int kt = 0; kt < K; kt += 32) {
        glds16(A  + (size_t)(row0 + r0s) * K + kt + k0s, &As[c0 * 8]);
        glds16(A  + (size_t)(row0 + r1s) * K + kt + k1s, &As[c1 * 8]);
        glds16(Wt + (size_t)(col0 + r0s) * K + kt + k0s, &Bs[c0 * 8]);
        glds16(Wt + (size_t)(col0 + r1s) * K + kt + k1s, &Bs[c1 * 8]);
        __syncthreads();
        shortx8 af[4], bf[4];
#pragma unroll
        for (int i = 0; i < 4; ++i)
            af[i] = *reinterpret_cast<const shortx8*>(&As[(wr + i * 16 + am) * 32 + aq]);
#pragma unroll
        for (int j = 0; j < 4; ++j)
            bf[j] = *reinterpret_cast<const shortx8*>(&Bs[(wc + j * 16 + am) * 32 + aq]);
#pragma unroll
        for (int i = 0; i < 4; ++i)
#pragma unroll
            for (int j = 0; j < 4; ++j)
                acc[i][j] = __builtin_amdgcn_mfma_f32_16x16x32_bf16(af[i], bf[j], acc[i][j], 0, 0, 0);
        __syncthreads();
    }

    const int cq = (lane >> 4) * 4;
    const int cn = lane & 15;
#pragma unroll
    for (int i = 0; i < 4; ++i) {
#pragma unroll
        for (int j = 0; j < 4; ++j) {
            const int n = col0 + wc + j * 16 + cn;
            const float bb = bias[n];
#pragma unroll
            for (int r = 0; r < 4; ++r) {
                const int m = row0 + wr + i * 16 + cq + r;
                float v = acc[i][j][r] + bb;
                if (SILU) v = v / (1.0f + __expf(-v));
                if (HAS_RES) v += res[(size_t)m * N + n];
                if (OUT_BF16) ((unsigned short*)outP)[(size_t)m * N + n] = f2bf(v);
                else          ((float*)outP)[(size_t)m * N + n] = v;
            }
        }
    }
}

// ---------- Fused QKV GEMM: N=3072 over concatenated [3072][1024] weights ----------
// col block 0..7 -> Q (pre-scaled by 1/8), 8..15 -> K, 16..23 -> V (transposed [1024][ROWS])
__global__ __launch_bounds__(256) void mfma_gemm_qkv(const unsigned short* __restrict__ A,
                                                     const unsigned short* __restrict__ Wt,
                                                     const float* __restrict__ bq,
                                                     const float* __restrict__ bk,
                                                     const float* __restrict__ bv,
                                                     unsigned short* __restrict__ qb,
                                                     unsigned short* __restrict__ kb,
                                                     unsigned short* __restrict__ vtb) {
    const int K = D_MODEL, M = ROWS;
    __shared__ unsigned short As[128 * 32];
    __shared__ unsigned short Bs[128 * 32];
    const int tid  = threadIdx.x;
    const int lane = tid & 63;
    const int wave = tid >> 6;
    const int row0 = blockIdx.y * 128, col0 = blockIdx.x * 128;
    const int wr = (wave >> 1) * 64, wc = (wave & 1) * 64;

    floatx4 acc[4][4] = {};
    const int c0 = tid,       r0s = c0 >> 2, k0s = (c0 & 3) * 8;
    const int c1 = tid + 256, r1s = c1 >> 2, k1s = (c1 & 3) * 8;
    const int am = (lane & 15), aq = (lane >> 4) * 8;

    for (int kt = 0; kt < K; kt += 32) {
        glds16(A  + (size_t)(row0 + r0s) * K + kt + k0s, &As[c0 * 8]);
        glds16(A  + (size_t)(row0 + r1s) * K + kt + k1s, &As[c1 * 8]);
        glds16(Wt + (size_t)(col0 + r0s) * K + kt + k0s, &Bs[c0 * 8]);
        glds16(Wt + (size_t)(col0 + r1s) * K + kt + k1s, &Bs[c1 * 8]);
        __syncthreads();
        shortx8 af[4], bf[4];
#pragma unroll
        for (int i = 0; i < 4; ++i)
            af[i] = *reinterpret_cast<const shortx8*>(&As[(wr + i * 16 + am) * 32 + aq]);
#pragma unroll
        for (int j = 0; j < 4; ++j)
            bf[j] = *reinterpret_cast<const shortx8*>(&Bs[(wc + j * 16 + am) * 32 + aq]);
#pragma unroll
        for (int i = 0; i < 4; ++i)
#pragma unroll
            for (int j = 0; j < 4; ++j)
                acc[i][j] = __builtin_amdgcn_mfma_f32_16x16x32_bf16(af[i], bf[j], acc[i][j], 0, 0, 0);
        __syncthreads();
    }

    const int cq = (lane >> 4) * 4;
    const int cn = lane & 15;
    const int sel = col0 >> 10;                 // 0=Q 1=K 2=V (block-uniform)
    const int nbase = col0 & 1023;
    const float* bias = (sel == 0) ? bq : (sel == 1) ? bk : bv;
    const float scl = (sel == 0) ? 0.125f : 1.0f;   // fold 1/sqrt(Dk) into Q (exact)
#pragma unroll
    for (int i = 0; i < 4; ++i) {
#pragma unroll
        for (int j = 0; j < 4; ++j) {
            const int n = nbase + wc + j * 16 + cn;
            const float bb = bias[n];
            if (sel == 2) {
                const int m0 = row0 + wr + i * 16 + cq;
                ushort4 o;
                o.x = f2bf(acc[i][j][0] + bb);
                o.y = f2bf(acc[i][j][1] + bb);
                o.z = f2bf(acc[i][j][2] + bb);
                o.w = f2bf(acc[i][j][3] + bb);
                *reinterpret_cast<ushort4*>(&vtb[(size_t)n * M + m0]) = o;
            } else {
                unsigned short* dst = (sel == 0) ? qb : kb;
#pragma unroll
                for (int r = 0; r < 4; ++r) {
                    const int m = row0 + wr + i * 16 + cq + r;
                    dst[(size_t)m * D_MODEL + n] = f2bf((acc[i][j][r] + bb) * scl);
                }
            }
        }
    }
}

// ---------- Split-K GEMM: z = K-slice; raw bf16 partials ----------
__global__ __launch_bounds__(256) void mfma_gemm_splitk(const unsigned short* __restrict__ A,
                                                        const unsigned short* __restrict__ Wt,
                                                        unsigned short* __restrict__ parts,
                                                        int M, int N, int KS) {
    __shared__ unsigned short As[128 * 32];
    __shared__ unsigned short Bs[128 * 32];
    const int tid  = threadIdx.x;
    const int lane = tid & 63;
    const int wave = tid >> 6;
    const int row0 = blockIdx.y * 128, col0 = blockIdx.x * 128;
    const int wr = (wave >> 1) * 64, wc = (wave & 1) * 64;
    const int K = KS * gridDim.z;
    const int kbeg = blockIdx.z * KS;
    unsigned short* outp = parts + (size_t)blockIdx.z * M * N;

    floatx4 acc[4][4] = {};
    const int c0 = tid,       r0s = c0 >> 2, k0s = (c0 & 3) * 8;
    const int c1 = tid + 256, r1s = c1 >> 2, k1s = (c1 & 3) * 8;
    const int am = (lane & 15), aq = (lane >> 4) * 8;

    for (int kt = kbeg; kt < kbeg + KS; kt += 32) {
        glds16(A  + (size_t)(row0 + r0s) * K + kt + k0s, &As[c0 * 8]);
        glds16(A  + (size_t)(row0 + r1s) * K + kt + k1s, &As[c1 * 8]);
        glds16(Wt + (size_t)(col0 + r0s) * K + kt + k0s, &Bs[c0 * 8]);
        glds16(Wt + (size_t)(col0 + r1s) * K + kt + k1s, &Bs[c1 * 8]);
        __syncthreads();
        shortx8 af[4], bf[4];
#pragma unroll
        for (int i = 0; i < 4; ++i)
            af[i] = *reinterpret_cast<const shortx8*>(&As[(wr + i * 16 + am) * 32 + aq]);
#pragma unroll
        for (int j = 0; j < 4; ++j)
            bf[j] = *reinterpret_cast<const shortx8*>(&Bs[(wc + j * 16 + am) * 32 + aq]);
#pragma unroll
        for (int i = 0; i < 4; ++i)
#pragma unroll
            for (int j = 0; j < 4; ++j)
                acc[i][j] = __builtin_amdgcn_mfma_f32_16x16x32_bf16(af[i], bf[j], acc[i][j], 0, 0, 0);
        __syncthreads();
    }

    const int cq = (lane >> 4) * 4;
    const int cn = lane & 15;
#pragma unroll
    for (int i = 0; i < 4; ++i)
#pragma unroll
        for (int j = 0; j < 4; ++j) {
            const int n = col0 + wc + j * 16 + cn;
#pragma unroll
            for (int r = 0; r < 4; ++r) {
                const int m = row0 + wr + i * 16 + cq + r;
                outp[(size_t)m * N + n] = f2bf(acc[i][j][r]);
            }
        }
}

// ---------- combine: out = p0 + p1 + bias + res ----------
__global__ __launch_bounds__(256) void combine_kernel(const unsigned short* __restrict__ p0,
                                                      const unsigned short* __restrict__ p1,
                                                      const float* __restrict__ bias,
                                                      const float* __restrict__ res,
                                                      float* __restrict__ out) {
    const size_t e0 = ((size_t)blockIdx.x * 256 + threadIdx.x) * 4;
    const int col = (int)(e0 & 1023);
    ushort4 a = *reinterpret_cast<const ushort4*>(&p0[e0]);
    ushort4 b = *reinterpret_cast<const ushort4*>(&p1[e0]);
    float4 r = *reinterpret_cast<const float4*>(&res[e0]);
    float4 o;
    o.x = bf2f(a.x) + bf2f(b.x) + bias[col + 0] + r.x;
    o.y = bf2f(a.y) + bf2f(b.y) + bias[col + 1] + r.y;
    o.z = bf2f(a.z) + bf2f(b.z) + bias[col + 2] + r.z;
    o.w = bf2f(a.w) + bf2f(b.w) + bias[col + 3] + r.w;
    *reinterpret_cast<float4*>(&out[e0]) = o;
}

// ---------- MFMA attention: one block per (b, h, 64-q-tile); 4 waves, 16-row strip each
// Q (pre-scaled 1/8), K bf16 [B*L][H*Dk]; Vt bf16 [H*Dk][B*L]; att bf16 [B*L][H*Dk].
// Stride-68 LDS rows: conflict-free (measured R9: SQ_LDS_BANK_CONFLICT = 0).
__global__ __launch_bounds__(256) void attn_mfma(const unsigned short* __restrict__ Q,
                                                 const unsigned short* __restrict__ K,
                                                 const unsigned short* __restrict__ Vt,
                                                 const int* __restrict__ mask,
                                                 unsigned short* __restrict__ att) {
    const int tid  = threadIdx.x;
    const int lane = tid & 63;
    const int wave = tid >> 6;
    const int q0 = blockIdx.x * 64;
    const int h  = blockIdx.y;
    const int b  = blockIdx.z;

    __shared__ unsigned short Qs[64 * PST];
    __shared__ unsigned short Ks[64 * PST];
    __shared__ unsigned short Vs[64 * PST];
    __shared__ unsigned short Ps[64 * PST];
    __shared__ int mk[64];

    const int am = lane & 15;
    const int aq = (lane >> 4) * 8;
    const int cq = (lane >> 4) * 4;
    const int cn = lane & 15;

    for (int c = tid; c < 512; c += 256) {
        const int r = c >> 3, off = (c & 7) * 8;
        *reinterpret_cast<uint4*>(&Qs[r * PST + off]) =
            *reinterpret_cast<const uint4*>(&Q[(size_t)(b * L_SEQ + q0 + r) * D_MODEL + h * D_K + off]);
    }
    __syncthreads();

    shortx8 aQ[2];
    aQ[0] = *reinterpret_cast<const shortx8*>(&Qs[(wave * 16 + am) * PST + aq]);
    aQ[1] = *reinterpret_cast<const shortx8*>(&Qs[(wave * 16 + am) * PST + 32 + aq]);

    floatx4 oacc[4] = {};
    float lsum[4] = {0.0f, 0.0f, 0.0f, 0.0f};

    for (int j0 = 0; j0 < L_SEQ; j0 += 64) {
        __syncthreads();
        for (int c = tid; c < 512; c += 256) {
            const int r = c >> 3, off = (c & 7) * 8;
            *reinterpret_cast<uint4*>(&Ks[r * PST + off]) =
                *reinterpret_cast<const uint4*>(&K[(size_t)(b * L_SEQ + j0 + r) * D_MODEL + h * D_K + off]);
            *reinterpret_cast<uint4*>(&Vs[r * PST + off]) =
                *reinterpret_cast<const uint4*>(&Vt[(size_t)(h * D_K + r) * ROWS + b * L_SEQ + j0 + off]);
        }
        if (tid < 64) mk[tid] = mask[b * L_SEQ + j0 + tid];
        __syncthreads();

        floatx4 sacc[4] = {};
#pragma unroll
        for (int kt = 0; kt < 2; ++kt)
#pragma unroll
            for (int jt = 0; jt < 4; ++jt) {
                shortx8 bK = *reinterpret_cast<const shortx8*>(&Ks[(jt * 16 + am) * PST + kt * 32 + aq]);
                sacc[jt] = __builtin_amdgcn_mfma_f32_16x16x32_bf16(aQ[kt], bK, sacc[jt], 0, 0, 0);
            }
        // P = exp(S) masked (Q pre-scaled); truncate-cast to bf16
#pragma unroll
        for (int jt = 0; jt < 4; ++jt) {
            const int mv = mk[jt * 16 + cn];
#pragma unroll
            for (int r = 0; r < 4; ++r) {
                float p = mv ? __expf(sacc[jt][r]) : 0.0f;
                lsum[r] += p;
                Ps[(wave * 16 + cq + r) * PST + jt * 16 + cn] =
                    (unsigned short)(__float_as_uint(p) >> 16);
            }
        }
        // O += P x V (wave-private Ps rows)
#pragma unroll
        for (int kt = 0; kt < 2; ++kt) {
            shortx8 aP = *reinterpret_cast<const shortx8*>(&Ps[(wave * 16 + am) * PST + kt * 32 + aq]);
#pragma unroll
            for (int dt = 0; dt < 4; ++dt) {
                shortx8 bV = *reinterpret_cast<const shortx8*>(&Vs[(dt * 16 + am) * PST + kt * 32 + aq]);
                oacc[dt] = __builtin_amdgcn_mfma_f32_16x16x32_bf16(aP, bV, oacc[dt], 0, 0, 0);
            }
        }
    }

#pragma unroll
    for (int r = 0; r < 4; ++r) {
        float t = lsum[r];
        t += __shfl_xor(t, 1);
        t += __shfl_xor(t, 2);
        t += __shfl_xor(t, 4);
        t += __shfl_xor(t, 8);
        lsum[r] = 1.0f / t;
    }
#pragma unroll
    for (int dt = 0; dt < 4; ++dt)
#pragma unroll
        for (int r = 0; r < 4; ++r) {
            att[(size_t)(b * L_SEQ + q0 + wave * 16 + cq + r) * D_MODEL + h * D_K + dt * 16 + cn] =
                f2bf(oacc[dt][r] * lsum[r]);
        }
}

extern "C" void kernel_launch(void* const* d_in, const int* in_sizes, int n_in,
                              void* d_out, int out_size, void* d_ws, size_t ws_size,
                              hipStream_t stream) {
    const float* x     = (const float*)d_in[0];
    const int*   mask  = (const int*)d_in[1];
    const float* ln1_g = (const float*)d_in[2];
    const float* ln1_b = (const float*)d_in[3];
    const float* Wq    = (const float*)d_in[4];
    const float* bq    = (const float*)d_in[5];
    const float* Wk    = (const float*)d_in[6];
    const float* bk    = (const float*)d_in[7];
    const float* Wv    = (const float*)d_in[8];
    const float* bv    = (const float*)d_in[9];
    const float* Wo    = (const float*)d_in[10];
    const float* bo    = (const float*)d_in[11];
    const float* ln2_g = (const float*)d_in[12];
    const float* ln2_b = (const float*)d_in[13];
    const float* W1    = (const float*)d_in[14];
    const float* b1    = (const float*)d_in[15];
    const float* W2    = (const float*)d_in[16];
    const float* b2    = (const float*)d_in[17];
    float* out = (float*)d_out;

    float* ws = (float*)d_ws;
    const size_t SZ = (size_t)ROWS * D_MODEL;  // 4M elements; fp32 slot = 16 MB

    unsigned short* nx  = (unsigned short*)(ws + 0 * SZ);   // 0-8 MB: LN1/LN2 out bf16
    unsigned short* qb  = (unsigned short*)(ws + 1 * SZ);   // 16-24: Q bf16 (pre-scaled)
    unsigned short* kb  = qb + SZ;                          // 24-32: K bf16
    unsigned short* vtb = (unsigned short*)(ws + 2 * SZ);   // 32-40: V^T bf16
    unsigned short* attb = vtb + SZ;                        // 40-48: att bf16
    float* x1  = out;                                       // residual stream in d_out
    unsigned short* nx2 = nx;                               // slot0 reuse
    unsigned short* h = (unsigned short*)(ws + 2 * SZ);     // 32-64: FFN hidden bf16
    unsigned short* parts = (unsigned short*)(ws + 0 * SZ); // 0-16: FFN2 split-K partials

    unsigned short* WqkvT = (unsigned short*)(ws + 4 * SZ); // 64-70: concat [3072][1024]
    unsigned short* WqT = WqkvT;
    unsigned short* WkT = WqkvT + (size_t)D_MODEL * D_MODEL;
    unsigned short* WvT = WkT + (size_t)D_MODEL * D_MODEL;
    unsigned short* WoT = WvT + (size_t)D_MODEL * D_MODEL;  // 70-72
    unsigned short* W1T = (unsigned short*)(ws + 1 * SZ);   // 16-24 (qb/kb dead after attn)
    unsigned short* W2T = W1T + (size_t)D_MODEL * FFN_DIM;  // 24-32

    ln_kernel<<<ROWS, 256, 0, stream>>>(x, ln1_g, ln1_b, nx);

    transpose_cast4<<<dim3(32, 32, 4), 256, 0, stream>>>(Wq, Wk, Wv, Wo, WqT, WkT, WvT, WoT);

    mfma_gemm_qkv<<<dim3(3072 / 128, ROWS / 128), 256, 0, stream>>>(
        nx, WqkvT, bq, bk, bv, qb, kb, vtb);

    attn_mfma<<<dim3(L_SEQ / 64, N_HEAD, B_SZ), 256, 0, stream>>>(qb, kb, vtb, mask, attb);

    transpose_cast<<<dim3(FFN_DIM / 32, D_MODEL / 32), 256, 0, stream>>>(W1, W1T, D_MODEL, FFN_DIM);
    transpose_cast<<<dim3(D_MODEL / 32, FFN_DIM / 32), 256, 0, stream>>>(W2, W2T, FFN_DIM, D_MODEL);

    mfma_gemm<0, 1, 0><<<dim3(D_MODEL / 128, ROWS / 128), 256, 0, stream>>>(
        attb, WoT, bo, x, x1, ROWS, D_MODEL, D_MODEL);

    ln_kernel<<<ROWS, 256, 0, stream>>>(x1, ln2_g, ln2_b, nx2);

    mfma_gemm<1, 0, 1><<<dim3(FFN_DIM / 128, ROWS / 128), 256, 0, stream>>>(
        nx2, W1T, b1, nullptr, h, ROWS, FFN_DIM, D_MODEL);

    mfma_gemm_splitk<<<dim3(D_MODEL / 128, ROWS / 128, 2), 256, 0, stream>>>(
        h, W2T, parts, ROWS, D_MODEL, FFN_DIM / 2);
    combine_kernel<<<(ROWS * D_MODEL) / 1024, 256, 0, stream>>>(
        parts, parts + SZ, b2, x1, out);
}

// Round 11
// 414.260 us; speedup vs baseline: 1.0868x; 1.0509x over previous
//
#include <hip/hip_runtime.h>
#include <hip/hip_bf16.h>

#define D_MODEL 1024
#define N_HEAD  16
#define D_K     64
#define FFN_DIM 4096
#define B_SZ    2
#define L_SEQ   2048
#define ROWS    (B_SZ * L_SEQ)   // 4096
#define PST     68               // Ps/Qs LDS row stride (shorts): proven 0-conflict (R9/R10)

typedef float  floatx4 __attribute__((ext_vector_type(4)));
typedef short  shortx8 __attribute__((ext_vector_type(8)));

__device__ __forceinline__ unsigned short f2bf(float f) {
    unsigned int u = __float_as_uint(f);
    unsigned int rounding = 0x7fffu + ((u >> 16) & 1u);
    return (unsigned short)((u + rounding) >> 16);
}
__device__ __forceinline__ float bf2f(unsigned short u) {
    return __uint_as_float(((unsigned int)u) << 16);
}

// async global->LDS 16B copy; LDS dest is wave-uniform base + lane*16
__device__ __forceinline__ void glds16(const unsigned short* g, unsigned short* l) {
    __builtin_amdgcn_global_load_lds(
        (const __attribute__((address_space(1))) unsigned int*)g,
        (__attribute__((address_space(3))) unsigned int*)l, 16, 0, 0);
}

// ---------- LayerNorm: one block per row of 1024, fp32 in -> bf16 out ----------
__global__ __launch_bounds__(256) void ln_kernel(const float* __restrict__ x,
                                                 const float* __restrict__ g,
                                                 const float* __restrict__ b,
                                                 unsigned short* __restrict__ out) {
    const int row = blockIdx.x;
    const int tid = threadIdx.x;
    const float* xr = x + (size_t)row * D_MODEL;
    float4 xv = *reinterpret_cast<const float4*>(&xr[tid * 4]);
    float v[4] = {xv.x, xv.y, xv.z, xv.w};
    float s = v[0] + v[1] + v[2] + v[3];
    float ss = v[0] * v[0] + v[1] * v[1] + v[2] * v[2] + v[3] * v[3];
    __shared__ float r1[256], r2[256];
    r1[tid] = s; r2[tid] = ss;
    __syncthreads();
    for (int off = 128; off > 0; off >>= 1) {
        if (tid < off) { r1[tid] += r1[tid + off]; r2[tid] += r2[tid + off]; }
        __syncthreads();
    }
    const float mean = r1[0] * (1.0f / D_MODEL);
    const float var  = r2[0] * (1.0f / D_MODEL) - mean * mean;
    const float inv  = rsqrtf(var + 1e-5f);
    unsigned short* orow = out + (size_t)row * D_MODEL;
    ushort4 o;
    o.x = f2bf((v[0] - mean) * inv * g[tid * 4 + 0] + b[tid * 4 + 0]);
    o.y = f2bf((v[1] - mean) * inv * g[tid * 4 + 1] + b[tid * 4 + 1]);
    o.z = f2bf((v[2] - mean) * inv * g[tid * 4 + 2] + b[tid * 4 + 2]);
    o.w = f2bf((v[3] - mean) * inv * g[tid * 4 + 3] + b[tid * 4 + 3]);
    *reinterpret_cast<ushort4*>(&orow[tid * 4]) = o;
}

// ---------- Transpose+cast: W fp32 [K][N] -> Wt bf16 [N][K] ----------
__global__ __launch_bounds__(256) void transpose_cast(const float* __restrict__ W,
                                                      unsigned short* __restrict__ Wt,
                                                      int K, int N) {
    __shared__ unsigned short T[32][33];
    const int t = threadIdx.x;
    const int k0 = blockIdx.y * 32, n0 = blockIdx.x * 32;
    const int kr = t >> 3, nc = (t & 7) * 4;
    float4 w = *reinterpret_cast<const float4*>(&W[(size_t)(k0 + kr) * N + n0 + nc]);
    T[kr][nc + 0] = f2bf(w.x); T[kr][nc + 1] = f2bf(w.y);
    T[kr][nc + 2] = f2bf(w.z); T[kr][nc + 3] = f2bf(w.w);
    __syncthreads();
    const int nr = t >> 3, kc = (t & 7) * 4;
    ushort4 o;
    o.x = T[kc + 0][nr]; o.y = T[kc + 1][nr];
    o.z = T[kc + 2][nr]; o.w = T[kc + 3][nr];
    *reinterpret_cast<ushort4*>(&Wt[(size_t)(n0 + nr) * K + k0 + kc]) = o;
}

// ---------- 4x square (1024x1024) transpose in one dispatch, z selects matrix ----------
__global__ __launch_bounds__(256) void transpose_cast4(const float* s0, const float* s1,
                                                       const float* s2, const float* s3,
                                                       unsigned short* d0, unsigned short* d1,
                                                       unsigned short* d2, unsigned short* d3) {
    const int z = blockIdx.z;
    const float* W = (z == 0) ? s0 : (z == 1) ? s1 : (z == 2) ? s2 : s3;
    unsigned short* Wt = (z == 0) ? d0 : (z == 1) ? d1 : (z == 2) ? d2 : d3;
    __shared__ unsigned short T[32][33];
    const int t = threadIdx.x;
    const int k0 = blockIdx.y * 32, n0 = blockIdx.x * 32;
    const int kr = t >> 3, nc = (t & 7) * 4;
    float4 w = *reinterpret_cast<const float4*>(&W[(size_t)(k0 + kr) * D_MODEL + n0 + nc]);
    T[kr][nc + 0] = f2bf(w.x); T[kr][nc + 1] = f2bf(w.y);
    T[kr][nc + 2] = f2bf(w.z); T[kr][nc + 3] = f2bf(w.w);
    __syncthreads();
    const int nr = t >> 3, kc = (t & 7) * 4;
    ushort4 o;
    o.x = T[kc + 0][nr]; o.y = T[kc + 1][nr];
    o.z = T[kc + 2][nr]; o.w = T[kc + 3][nr];
    *reinterpret_cast<ushort4*>(&Wt[(size_t)(n0 + nr) * D_MODEL + k0 + kc]) = o;
}

// ===== GEMM swizzle: tile = 128 rows x 32 shorts (4x16B chunks/row).
// LDS pos p holds global chunk (row=p>>2, kc=((p&3)-(row>>1))&3).
// Read of (R, kc) at p = R*4 + ((kc+(R>>1))&3) -> bank-group 2-way max (free).

// ---------- MFMA bf16 GEMM (async swizzled staging). A [M][K]; Wt [N][K]. 128x128, BK=32. ----------
template <int SILU, int HAS_RES, int OUT_BF16>
__global__ __launch_bounds__(256) void mfma_gemm(const unsigned short* __restrict__ A,
                                                 const unsigned short* __restrict__ Wt,
                                                 const float* __restrict__ bias,
                                                 const float* __restrict__ res,
                                                 void* __restrict__ outP,
                                                 int M, int N, int K) {
    __shared__ unsigned short As[128 * 32];
    __shared__ unsigned short Bs[128 * 32];
    const int tid  = threadIdx.x;
    const int lane = tid & 63;
    const int wave = tid >> 6;
    const int row0 = blockIdx.y * 128, col0 = blockIdx.x * 128;
    const int wr = (wave >> 1) * 64, wc = (wave & 1) * 64;

    floatx4 acc[4][4] = {};
    const int p0 = tid,       r0s = p0 >> 2, k0s = (((p0 & 3) - (r0s >> 1)) & 3) * 8;
    const int p1 = tid + 256, r1s = p1 >> 2, k1s = (((p1 & 3) - (r1s >> 1)) & 3) * 8;
    const int am = (lane & 15);

    int offA[4], offB[4];
#pragma unroll
    for (int i = 0; i < 4; ++i) {
        const int Ra = wr + i * 16 + am;
        offA[i] = Ra * 32 + (((lane >> 4) + (Ra >> 1)) & 3) * 8;
        const int Rb = wc + i * 16 + am;
        offB[i] = Rb * 32 + (((lane >> 4) + (Rb >> 1)) & 3) * 8;
    }

    for (int kt = 0; kt < K; kt += 32) {
        glds16(A  + (size_t)(row0 + r0s) * K + kt + k0s, &As[p0 * 8]);
        glds16(A  + (size_t)(row0 + r1s) * K + kt + k1s, &As[p1 * 8]);
        glds16(Wt + (size_t)(col0 + r0s) * K + kt + k0s, &Bs[p0 * 8]);
        glds16(Wt + (size_t)(col0 + r1s) * K + kt + k1s, &Bs[p1 * 8]);
        __syncthreads();
        shortx8 af[4], bf[4];
#pragma unroll
        for (int i = 0; i < 4; ++i)
            af[i] = *reinterpret_cast<const shortx8*>(&As[offA[i]]);
#pragma unroll
        for (int j = 0; j < 4; ++j)
            bf[j] = *reinterpret_cast<const shortx8*>(&Bs[offB[j]]);
#pragma unroll
        for (int i = 0; i < 4; ++i)
#pragma unroll
            for (int j = 0; j < 4; ++j)
                acc[i][j] = __builtin_amdgcn_mfma_f32_16x16x32_bf16(af[i], bf[j], acc[i][j], 0, 0, 0);
        __syncthreads();
    }

    const int cq = (lane >> 4) * 4;
    const int cn = lane & 15;
#pragma unroll
    for (int i = 0; i < 4; ++i) {
#pragma unroll
        for (int j = 0; j < 4; ++j) {
            const int n = col0 + wc + j * 16 + cn;
            const float bb = bias[n];
#pragma unroll
            for (int r = 0; r < 4; ++r) {
                const int m = row0 + wr + i * 16 + cq + r;
                float v = acc[i][j][r] + bb;
                if (SILU) v = v / (1.0f + __expf(-v));
                if (HAS_RES) v += res[(size_t)m * N + n];
                if (OUT_BF16) ((unsigned short*)outP)[(size_t)m * N + n] = f2bf(v);
                else          ((float*)outP)[(size_t)m * N + n] = v;
            }
        }
    }
}

// ---------- Fused QKV GEMM: N=3072 over concatenated [3072][1024] weights ----------
__global__ __launch_bounds__(256) void mfma_gemm_qkv(const unsigned short* __restrict__ A,
                                                     const unsigned short* __restrict__ Wt,
                                                     const float* __restrict__ bq,
                                                     const float* __restrict__ bk,
                                                     const float* __restrict__ bv,
                                                     unsigned short* __restrict__ qb,
                                                     unsigned short* __restrict__ kb,
                                                     unsigned short* __restrict__ vtb) {
    const int K = D_MODEL, M = ROWS;
    __shared__ unsigned short As[128 * 32];
    __shared__ unsigned short Bs[128 * 32];
    const int tid  = threadIdx.x;
    const int lane = tid & 63;
    const int wave = tid >> 6;
    const int row0 = blockIdx.y * 128, col0 = blockIdx.x * 128;
    const int wr = (wave >> 1) * 64, wc = (wave & 1) * 64;

    floatx4 acc[4][4] = {};
    const int p0 = tid,       r0s = p0 >> 2, k0s = (((p0 & 3) - (r0s >> 1)) & 3) * 8;
    const int p1 = tid + 256, r1s = p1 >> 2, k1s = (((p1 & 3) - (r1s >> 1)) & 3) * 8;
    const int am = (lane & 15);

    int offA[4], offB[4];
#pragma unroll
    for (int i = 0; i < 4; ++i) {
        const int Ra = wr + i * 16 + am;
        offA[i] = Ra * 32 + (((lane >> 4) + (Ra >> 1)) & 3) * 8;
        const int Rb = wc + i * 16 + am;
        offB[i] = Rb * 32 + (((lane >> 4) + (Rb >> 1)) & 3) * 8;
    }

    for (int kt = 0; kt < K; kt += 32) {
        glds16(A  + (size_t)(row0 + r0s) * K + kt + k0s, &As[p0 * 8]);
        glds16(A  + (size_t)(row0 + r1s) * K + kt + k1s, &As[p1 * 8]);
        glds16(Wt + (size_t)(col0 + r0s) * K + kt + k0s, &Bs[p0 * 8]);
        glds16(Wt + (size_t)(col0 + r1s) * K + kt + k1s, &Bs[p1 * 8]);
        __syncthreads();
        shortx8 af[4], bf[4];
#pragma unroll
        for (int i = 0; i < 4; ++i)
            af[i] = *reinterpret_cast<const shortx8*>(&As[offA[i]]);
#pragma unroll
        for (int j = 0; j < 4; ++j)
            bf[j] = *reinterpret_cast<const shortx8*>(&Bs[offB[j]]);
#pragma unroll
        for (int i = 0; i < 4; ++i)
#pragma unroll
            for (int j = 0; j < 4; ++j)
                acc[i][j] = __builtin_amdgcn_mfma_f32_16x16x32_bf16(af[i], bf[j], acc[i][j], 0, 0, 0);
        __syncthreads();
    }

    const int cq = (lane >> 4) * 4;
    const int cn = lane & 15;
    const int sel = col0 >> 10;                 // 0=Q 1=K 2=V (block-uniform)
    const int nbase = col0 & 1023;
    const float* bias = (sel == 0) ? bq : (sel == 1) ? bk : bv;
    const float scl = (sel == 0) ? 0.125f : 1.0f;   // fold 1/sqrt(Dk) into Q (exact)
#pragma unroll
    for (int i = 0; i < 4; ++i) {
#pragma unroll
        for (int j = 0; j < 4; ++j) {
            const int n = nbase + wc + j * 16 + cn;
            const float bb = bias[n];
            if (sel == 2) {
                const int m0 = row0 + wr + i * 16 + cq;
                ushort4 o;
                o.x = f2bf(acc[i][j][0] + bb);
                o.y = f2bf(acc[i][j][1] + bb);
                o.z = f2bf(acc[i][j][2] + bb);
                o.w = f2bf(acc[i][j][3] + bb);
                *reinterpret_cast<ushort4*>(&vtb[(size_t)n * M + m0]) = o;
            } else {
                unsigned short* dst = (sel == 0) ? qb : kb;
#pragma unroll
                for (int r = 0; r < 4; ++r) {
                    const int m = row0 + wr + i * 16 + cq + r;
                    dst[(size_t)m * D_MODEL + n] = f2bf((acc[i][j][r] + bb) * scl);
                }
            }
        }
    }
}

// ---------- Split-K GEMM: z = K-slice; raw bf16 partials ----------
__global__ __launch_bounds__(256) void mfma_gemm_splitk(const unsigned short* __restrict__ A,
                                                        const unsigned short* __restrict__ Wt,
                                                        unsigned short* __restrict__ parts,
                                                        int M, int N, int KS) {
    __shared__ unsigned short As[128 * 32];
    __shared__ unsigned short Bs[128 * 32];
    const int tid  = threadIdx.x;
    const int lane = tid & 63;
    const int wave = tid >> 6;
    const int row0 = blockIdx.y * 128, col0 = blockIdx.x * 128;
    const int wr = (wave >> 1) * 64, wc = (wave & 1) * 64;
    const int K = KS * gridDim.z;
    const int kbeg = blockIdx.z * KS;
    unsigned short* outp = parts + (size_t)blockIdx.z * M * N;

    floatx4 acc[4][4] = {};
    const int p0 = tid,       r0s = p0 >> 2, k0s = (((p0 & 3) - (r0s >> 1)) & 3) * 8;
    const int p1 = tid + 256, r1s = p1 >> 2, k1s = (((p1 & 3) - (r1s >> 1)) & 3) * 8;
    const int am = (lane & 15);

    int offA[4], offB[4];
#pragma unroll
    for (int i = 0; i < 4; ++i) {
        const int Ra = wr + i * 16 + am;
        offA[i] = Ra * 32 + (((lane >> 4) + (Ra >> 1)) & 3) * 8;
        const int Rb = wc + i * 16 + am;
        offB[i] = Rb * 32 + (((lane >> 4) + (Rb >> 1)) & 3) * 8;
    }

    for (int kt = kbeg; kt < kbeg + KS; kt += 32) {
        glds16(A  + (size_t)(row0 + r0s) * K + kt + k0s, &As[p0 * 8]);
        glds16(A  + (size_t)(row0 + r1s) * K + kt + k1s, &As[p1 * 8]);
        glds16(Wt + (size_t)(col0 + r0s) * K + kt + k0s, &Bs[p0 * 8]);
        glds16(Wt + (size_t)(col0 + r1s) * K + kt + k1s, &Bs[p1 * 8]);
        __syncthreads();
        shortx8 af[4], bf[4];
#pragma unroll
        for (int i = 0; i < 4; ++i)
            af[i] = *reinterpret_cast<const shortx8*>(&As[offA[i]]);
#pragma unroll
        for (int j = 0; j < 4; ++j)
            bf[j] = *reinterpret_cast<const shortx8*>(&Bs[offB[j]]);
#pragma unroll
        for (int i = 0; i < 4; ++i)
#pragma unroll
            for (int j = 0; j < 4; ++j)
                acc[i][j] = __builtin_amdgcn_mfma_f32_16x16x32_bf16(af[i], bf[j], acc[i][j], 0, 0, 0);
        __syncthreads();
    }

    const int cq = (lane >> 4) * 4;
    const int cn = lane & 15;
#pragma unroll
    for (int i = 0; i < 4; ++i)
#pragma unroll
        for (int j = 0; j < 4; ++j) {
            const int n = col0 + wc + j * 16 + cn;
#pragma unroll
            for (int r = 0; r < 4; ++r) {
                const int m = row0 + wr + i * 16 + cq + r;
                outp[(size_t)m * N + n] = f2bf(acc[i][j][r]);
            }
        }
}

// ---------- combine: out = p0 + p1 + bias + res ----------
__global__ __launch_bounds__(256) void combine_kernel(const unsigned short* __restrict__ p0,
                                                      const unsigned short* __restrict__ p1,
                                                      const float* __restrict__ bias,
                                                      const float* __restrict__ res,
                                                      float* __restrict__ out) {
    const size_t e0 = ((size_t)blockIdx.x * 256 + threadIdx.x) * 4;
    const int col = (int)(e0 & 1023);
    ushort4 a = *reinterpret_cast<const ushort4*>(&p0[e0]);
    ushort4 b = *reinterpret_cast<const ushort4*>(&p1[e0]);
    float4 r = *reinterpret_cast<const float4*>(&res[e0]);
    float4 o;
    o.x = bf2f(a.x) + bf2f(b.x) + bias[col + 0] + r.x;
    o.y = bf2f(a.y) + bf2f(b.y) + bias[col + 1] + r.y;
    o.z = bf2f(a.z) + bf2f(b.z) + bias[col + 2] + r.z;
    o.w = bf2f(a.w) + bf2f(b.w) + bias[col + 3] + r.w;
    *reinterpret_cast<float4*>(&out[e0]) = o;
}

// ---------- MFMA attention: one block per (b, h, 64-q-tile); 4 waves, 16-row strip each
// Q (pre-scaled 1/8), K bf16 [B*L][H*Dk]; Vt bf16 [H*Dk][B*L]; att bf16 [B*L][H*Dk].
// Ks/Vs: glds16-staged with swizzle (row*8 + ((c8+row)&7)); Qs/Ps padded stride 68.
__global__ __launch_bounds__(256) void attn_mfma(const unsigned short* __restrict__ Q,
                                                 const unsigned short* __restrict__ K,
                                                 const unsigned short* __restrict__ Vt,
                                                 const int* __restrict__ mask,
                                                 unsigned short* __restrict__ att) {
    const int tid  = threadIdx.x;
    const int lane = tid & 63;
    const int wave = tid >> 6;
    const int q0 = blockIdx.x * 64;
    const int h  = blockIdx.y;
    const int b  = blockIdx.z;

    __shared__ unsigned short Qs[64 * PST];
    __shared__ unsigned short Ks[64 * 64];
    __shared__ unsigned short Vs[64 * 64];
    __shared__ unsigned short Ps[64 * PST];
    __shared__ int mk[64];

    const int am = lane & 15;
    const int aq = (lane >> 4) * 8;
    const int cq = (lane >> 4) * 4;
    const int cn = lane & 15;

    // stage Q tile (once, via VGPR; padded layout)
    for (int c = tid; c < 512; c += 256) {
        const int r = c >> 3, off = (c & 7) * 8;
        *reinterpret_cast<uint4*>(&Qs[r * PST + off]) =
            *reinterpret_cast<const uint4*>(&Q[(size_t)(b * L_SEQ + q0 + r) * D_MODEL + h * D_K + off]);
    }

    // swizzled staging source precompute: LDS chunk p holds (row=p>>3, c8=((p&7)-row)&7)
    const int p0 = tid,       sr0 = p0 >> 3, sc0 = (((p0 & 7) - sr0) & 7) * 8;
    const int p1 = tid + 256, sr1 = p1 >> 3, sc1 = (((p1 & 7) - sr1) & 7) * 8;
    const unsigned short* K0 = K + (size_t)(b * L_SEQ + sr0) * D_MODEL + h * D_K + sc0;
    const unsigned short* K1 = K + (size_t)(b * L_SEQ + sr1) * D_MODEL + h * D_K + sc1;
    const unsigned short* V0 = Vt + (size_t)(h * D_K + sr0) * ROWS + b * L_SEQ + sc0;
    const unsigned short* V1 = Vt + (size_t)(h * D_K + sr1) * ROWS + b * L_SEQ + sc1;

    // fragment read offsets (loop-invariant): row R = t*16+am, chunk c8 = kt*4 + (lane>>4)
    int offF[2][4];
#pragma unroll
    for (int kt = 0; kt < 2; ++kt)
#pragma unroll
        for (int t = 0; t < 4; ++t) {
            const int R = t * 16 + am;
            offF[kt][t] = R * 64 + (((kt * 4 + (lane >> 4)) + R) & 7) * 8;
        }

    __syncthreads();

    shortx8 aQ[2];
    aQ[0] = *reinterpret_cast<const shortx8*>(&Qs[(wave * 16 + am) * PST + aq]);
    aQ[1] = *reinterpret_cast<const shortx8*>(&Qs[(wave * 16 + am) * PST + 32 + aq]);

    floatx4 oacc[4] = {};
    float lsum[4] = {0.0f, 0.0f, 0.0f, 0.0f};

    for (int j0 = 0; j0 < L_SEQ; j0 += 64) {
        __syncthreads();
        glds16(K0 + (size_t)j0 * D_MODEL, &Ks[p0 * 8]);
        glds16(K1 + (size_t)j0 * D_MODEL, &Ks[p1 * 8]);
        glds16(V0 + j0, &Vs[p0 * 8]);
        glds16(V1 + j0, &Vs[p1 * 8]);
        if (tid < 64) mk[tid] = mask[b * L_SEQ + j0 + tid];
        __syncthreads();

        floatx4 sacc[4] = {};
#pragma unroll
        for (int kt = 0; kt < 2; ++kt)
#pragma unroll
            for (int jt = 0; jt < 4; ++jt) {
                shortx8 bK = *reinterpret_cast<const shortx8*>(&Ks[offF[kt][jt]]);
                sacc[jt] = __builtin_amdgcn_mfma_f32_16x16x32_bf16(aQ[kt], bK, sacc[jt], 0, 0, 0);
            }
        // P = exp(S) masked (Q pre-scaled); truncate-cast to bf16
#pragma unroll
        for (int jt = 0; jt < 4; ++jt) {
            const int mv = mk[jt * 16 + cn];
#pragma unroll
            for (int r = 0; r < 4; ++r) {
                float p = mv ? __expf(sacc[jt][r]) : 0.0f;
                lsum[r] += p;
                Ps[(wave * 16 + cq + r) * PST + jt * 16 + cn] =
                    (unsigned short)(__float_as_uint(p) >> 16);
            }
        }
        // O += P x V (wave-private Ps rows)
#pragma unroll
        for (int kt = 0; kt < 2; ++kt) {
            shortx8 aP = *reinterpret_cast<const shortx8*>(&Ps[(wave * 16 + am) * PST + kt * 32 + aq]);
#pragma unroll
            for (int dt = 0; dt < 4; ++dt) {
                shortx8 bV = *reinterpret_cast<const shortx8*>(&Vs[offF[kt][dt]]);
                oacc[dt] = __builtin_amdgcn_mfma_f32_16x16x32_bf16(aP, bV, oacc[dt], 0, 0, 0);
            }
        }
    }

#pragma unroll
    for (int r = 0; r < 4; ++r) {
        float t = lsum[r];
        t += __shfl_xor(t, 1);
        t += __shfl_xor(t, 2);
        t += __shfl_xor(t, 4);
        t += __shfl_xor(t, 8);
        lsum[r] = 1.0f / t;
    }
#pragma unroll
    for (int dt = 0; dt < 4; ++dt)
#pragma unroll
        for (int r = 0; r < 4; ++r) {
            att[(size_t)(b * L_SEQ + q0 + wave * 16 + cq + r) * D_MODEL + h * D_K + dt * 16 + cn] =
                f2bf(oacc[dt][r] * lsum[r]);
        }
}

extern "C" void kernel_launch(void* const* d_in, const int* in_sizes, int n_in,
                              void* d_out, int out_size, void* d_ws, size_t ws_size,
                              hipStream_t stream) {
    const float* x     = (const float*)d_in[0];
    const int*   mask  = (const int*)d_in[1];
    const float* ln1_g = (const float*)d_in[2];
    const float* ln1_b = (const float*)d_in[3];
    const float* Wq    = (const float*)d_in[4];
    const float* bq    = (const float*)d_in[5];
    const float* Wk    = (const float*)d_in[6];
    const float* bk    = (const float*)d_in[7];
    const float* Wv    = (const float*)d_in[8];
    const float* bv    = (const float*)d_in[9];
    const float* Wo    = (const float*)d_in[10];
    const float* bo    = (const float*)d_in[11];
    const float* ln2_g = (const float*)d_in[12];
    const float* ln2_b = (const float*)d_in[13];
    const float* W1    = (const float*)d_in[14];
    const float* b1    = (const float*)d_in[15];
    const float* W2    = (const float*)d_in[16];
    const float* b2    = (const float*)d_in[17];
    float* out = (float*)d_out;

    float* ws = (float*)d_ws;
    const size_t SZ = (size_t)ROWS * D_MODEL;  // 4M elements; fp32 slot = 16 MB

    unsigned short* nx  = (unsigned short*)(ws + 0 * SZ);   // 0-8 MB: LN1/LN2 out bf16
    unsigned short* qb  = (unsigned short*)(ws + 1 * SZ);   // 16-24: Q bf16 (pre-scaled)
    unsigned short* kb  = qb + SZ;                          // 24-32: K bf16
    unsigned short* vtb = (unsigned short*)(ws + 2 * SZ);   // 32-40: V^T bf16
    unsigned short* attb = vtb + SZ;                        // 40-48: att bf16
    float* x1  = out;                                       // residual stream in d_out
    unsigned short* nx2 = nx;                               // slot0 reuse
    unsigned short* h = (unsigned short*)(ws + 2 * SZ);     // 32-64: FFN hidden bf16
    unsigned short* parts = (unsigned short*)(ws + 0 * SZ); // 0-16: FFN2 split-K partials

    unsigned short* WqkvT = (unsigned short*)(ws + 4 * SZ); // 64-70: concat [3072][1024]
    unsigned short* WqT = WqkvT;
    unsigned short* WkT = WqkvT + (size_t)D_MODEL * D_MODEL;
    unsigned short* WvT = WkT + (size_t)D_MODEL * D_MODEL;
    unsigned short* WoT = WvT + (size_t)D_MODEL * D_MODEL;  // 70-72
    unsigned short* W1T = (unsigned short*)(ws + 1 * SZ);   // 16-24 (qb/kb dead after attn)
    unsigned short* W2T = W1T + (size_t)D_MODEL * FFN_DIM;  // 24-32

    ln_kernel<<<ROWS, 256, 0, stream>>>(x, ln1_g, ln1_b, nx);

    transpose_cast4<<<dim3(32, 32, 4), 256, 0, stream>>>(Wq, Wk, Wv, Wo, WqT, WkT, WvT, WoT);

    mfma_gemm_qkv<<<dim3(3072 / 128, ROWS / 128), 256, 0, stream>>>(
        nx, WqkvT, bq, bk, bv, qb, kb, vtb);

    attn_mfma<<<dim3(L_SEQ / 64, N_HEAD, B_SZ), 256, 0, stream>>>(qb, kb, vtb, mask, attb);

    transpose_cast<<<dim3(FFN_DIM / 32, D_MODEL / 32), 256, 0, stream>>>(W1, W1T, D_MODEL, FFN_DIM);
    transpose_cast<<<dim3(D_MODEL / 32, FFN_DIM / 32), 256, 0, stream>>>(W2, W2T, FFN_DIM, D_MODEL);

    mfma_gemm<0, 1, 0><<<dim3(D_MODEL / 128, ROWS / 128), 256, 0, stream>>>(
        attb, WoT, bo, x, x1, ROWS, D_MODEL, D_MODEL);

    ln_kernel<<<ROWS, 256, 0, stream>>>(x1, ln2_g, ln2_b, nx2);

    mfma_gemm<1, 0, 1><<<dim3(FFN_DIM / 128, ROWS / 128), 256, 0, stream>>>(
        nx2, W1T, b1, nullptr, h, ROWS, FFN_DIM, D_MODEL);

    mfma_gemm_splitk<<<dim3(D_MODEL / 128, ROWS / 128, 2), 256, 0, stream>>>(
        h, W2T, parts, ROWS, D_MODEL, FFN_DIM / 2);
    combine_kernel<<<(ROWS * D_MODEL) / 1024, 256, 0, stream>>>(
        parts, parts + SZ, b2, x1, out);
}